// Round 1
// baseline (230.565 us; speedup 1.0000x reference)
//
#include <hip/hip_runtime.h>
#include <math.h>

#define BB 32
#define NN 32
#define AA 8400
#define CC 80
#define TK 13
#define TA 16

// Static device scratch (avoids ws_size assumptions). Fully rewritten each call.
__device__ float g_metrics[BB*NN*AA];
__device__ float g_overlaps[BB*NN*AA];
__device__ unsigned char g_maskin[BB*NN*AA];
__device__ unsigned char g_maskpos[BB*NN*AA];
__device__ float g_posalign[BB*NN];
__device__ float g_posov[BB*NN];
__device__ float g_norm[BB*AA];
__device__ int   g_fgcnt[BB*AA];
__device__ int   g_S[BB*CC];
__device__ int   g_fgcol[BB];

__device__ __forceinline__ float ciou_clip(float b1x1,float b1y1,float b1x2,float b1y2,
                                           float b2x1,float b2y1,float b2x2,float b2y2) {
  const float eps = 1e-7f;
  float w1 = b1x2-b1x1, h1 = b1y2-b1y1;
  float w2 = b2x2-b2x1, h2 = b2y2-b2y1;
  float iw = fmaxf(fminf(b1x2,b2x2) - fmaxf(b1x1,b2x1), 0.0f);
  float ih = fmaxf(fminf(b1y2,b2y2) - fmaxf(b1y1,b2y1), 0.0f);
  float inter = iw*ih;
  float uni = w1*h1 + w2*h2 - inter + eps;
  float iou = inter/uni;
  float cw = fmaxf(b1x2,b2x2) - fminf(b1x1,b2x1);
  float ch = fmaxf(b1y2,b2y2) - fminf(b1y1,b2y1);
  float c2 = cw*cw + ch*ch + eps;
  float dx = b2x1+b2x2-b1x1-b1x2;
  float dy = b2y1+b2y2-b1y1-b1y2;
  float rho2 = (dx*dx + dy*dy) / 4.0f;
  const float c4pi2 = (float)(4.0 / (M_PI * M_PI));
  float dat = atanf(w2/(h2+eps)) - atanf(w1/(h1+eps));
  float v = c4pi2 * (dat*dat);
  float alpha = v / (v - iou + (1.0f + 1e-7f));
  float ciou = iou - (rho2/c2 + v*alpha);
  return fmaxf(ciou, 0.0f);  // jnp.clip(x, 0.0)
}

// K1: per (b,j,a) -> overlaps, metrics, mask_in
__global__ __launch_bounds__(256) void k1(const float* __restrict__ pd_scores,
                                          const float* __restrict__ pd_bboxes,
                                          const float* __restrict__ anc,
                                          const int* __restrict__ gt_labels,
                                          const float* __restrict__ gt_bboxes) {
  int idx = blockIdx.x*256 + threadIdx.x;
  if (idx >= BB*NN*AA) return;
  int a = idx % AA;
  int bj = idx / AA;
  int b = bj / NN;
  float4 g = *(const float4*)&gt_bboxes[bj*4];
  float4 p = *(const float4*)&pd_bboxes[(size_t)(b*AA + a)*4];
  float ov = ciou_clip(g.x,g.y,g.z,g.w, p.x,p.y,p.z,p.w);
  int lab = gt_labels[bj];
  float score = pd_scores[(size_t)(b*AA + a)*CC + lab];
  float align = score * powf(ov, 6.0f);      // score**1.0 * ov**6.0
  float2 an = ((const float2*)anc)[a];
  float mn = fminf(fminf(an.x - g.x, an.y - g.y), fminf(g.z - an.x, g.w - an.y));
  unsigned char mi = (mn > 1e-9f) ? 1 : 0;
  g_metrics[idx]  = mi ? align : 0.0f;
  g_overlaps[idx] = ov;
  g_maskin[idx]   = mi;
}

// K2: one wave per (b,j): stable top-13, scatter mask_pos, pos_align/pos_ov
__global__ __launch_bounds__(64) void k2(const float* __restrict__ mask_gt) {
  int bj = blockIdx.x;
  int lane = threadIdx.x;
  __shared__ float sm[AA];
  __shared__ int sel[TK];
  const float* mrow = &g_metrics[(size_t)bj*AA];
  unsigned char* mp = &g_maskpos[(size_t)bj*AA];
  for (int a = lane; a < AA; a += 64) { sm[a] = mrow[a]; mp[a] = 0; }
  if ((bj % NN) == 0) {
    int b = bj / NN;
    for (int c = lane; c < CC; c += 64) g_S[b*CC + c] = 0;
  }
  __syncthreads();
  for (int t = 0; t < TK; ++t) {
    unsigned long long best = 0ull;
    for (int a = lane; a < AA; a += 64) {
      float m = sm[a];
      if (m >= 0.0f) {  // -1.0f marks removed; metrics are >= 0
        unsigned long long key = ((unsigned long long)__float_as_uint(m) << 32)
                               | (unsigned long long)(0xFFFFFFFFu - (unsigned)a);
        if (key > best) best = key;
      }
    }
    #pragma unroll
    for (int o = 32; o > 0; o >>= 1) {
      unsigned long long other = __shfl_xor(best, o, 64);
      if (other > best) best = other;
    }
    int widx = (int)(0xFFFFFFFFu - (unsigned)(best & 0xFFFFFFFFull));
    if (lane == 0) { sel[t] = widx; sm[widx] = -1.0f; }
    __syncthreads();
  }
  if (lane == 0) {
    float pa = 0.0f, po = 0.0f;
    if (mask_gt[bj] != 0.0f) {
      for (int t = 0; t < TK; ++t) {
        int a2 = sel[t];
        if (g_maskin[(size_t)bj*AA + a2]) {
          mp[a2] = 1;
          pa = fmaxf(pa, mrow[a2]);                       // metrics == align where mask_in=1
          po = fmaxf(po, g_overlaps[(size_t)bj*AA + a2]);
        }
      }
    }
    g_posalign[bj] = pa;
    g_posov[bj]   = po;
  }
}

// K3a: per (b,a): tgt, fg, bbox, norm; accumulate class histogram S
__global__ __launch_bounds__(256) void k3a(const float* __restrict__ gt_bboxes,
                                           const int* __restrict__ gt_labels,
                                           float* __restrict__ out_bbox,
                                           float* __restrict__ out_fg,
                                           float* __restrict__ out_tgt) {
  int b = blockIdx.y;
  int a = blockIdx.x*256 + threadIdx.x;
  int t = threadIdx.x;
  __shared__ __align__(16) float gtb[NN*4];
  __shared__ int lab[NN];
  __shared__ float pal[NN], pov[NN];
  __shared__ int Sl[CC];
  if (t < NN*4) gtb[t] = gt_bboxes[b*NN*4 + t];
  if (t < NN) { lab[t] = gt_labels[b*NN + t]; pal[t] = g_posalign[b*NN + t]; pov[t] = g_posov[b*NN + t]; }
  if (t < CC) Sl[t] = 0;
  __syncthreads();
  if (a < AA) {
    float ov[NN];
    unsigned mpb = 0;
    #pragma unroll
    for (int j = 0; j < NN; ++j) {
      size_t o = (size_t)(b*NN + j)*AA + a;
      ov[j] = g_overlaps[o];
      if (g_maskpos[o]) mpb |= (1u << j);
    }
    float maxo = ov[0];
    #pragma unroll
    for (int j = 1; j < NN; ++j) maxo = fmaxf(maxo, ov[j]);
    int jmax = 0, fg = 0, cnt0 = 0;
    float nrm = 0.0f;
    #pragma unroll
    for (int j = 0; j < NN; ++j) {
      bool m = (mpb >> j) & 1u;
      int tj = (m && (ov[j] == maxo)) ? j : 0;
      out_tgt[(size_t)(b*NN + j)*AA + a] = (float)tj;
      if (tj > jmax) jmax = tj;
      if (m) {
        ++fg;
        float al = g_metrics[(size_t)(b*NN + j)*AA + a];
        nrm = fmaxf(nrm, al * pov[j] / (pal[j] + 1e-9f));
      }
      if (tj > 0) atomicAdd(&Sl[lab[tj]], 1); else ++cnt0;
    }
    atomicAdd(&Sl[lab[0]], cnt0);
    out_fg[b*AA + a]  = fg > 0 ? 1.0f : 0.0f;
    g_fgcnt[b*AA + a] = fg;
    g_norm[b*AA + a]  = nrm;
    float4 bb = *(const float4*)&gtb[jmax*4];
    *(float4*)&out_bbox[(size_t)(b*AA + a)*4] = bb;
  }
  __syncthreads();
  if (t < CC) atomicAdd(&g_S[b*CC + t], Sl[t]);
}

// K3b: fg_columns[b] = argmax_c S[b,c] (first max)
__global__ __launch_bounds__(64) void k3b() {
  int b = threadIdx.x;
  if (b < BB) {
    int best = -1, bc = 0;
    for (int c = 0; c < CC; ++c) { int s = g_S[b*CC + c]; if (s > best) { best = s; bc = c; } }
    g_fgcol[b] = bc;
  }
}

// K3c: target_scores[b,a,c] = hard * norm
__global__ __launch_bounds__(256) void k3c(const int* __restrict__ gt_labels,
                                           const float* __restrict__ out_tgt,
                                           float* __restrict__ out_scores) {
  int b = blockIdx.y;
  int a0 = blockIdx.x * TA;
  int t = threadIdx.x;
  __shared__ int lab[NN];
  __shared__ int ltg[TA][NN];
  __shared__ float nr[TA];
  __shared__ int fgi[TA];
  if (t < NN) lab[t] = gt_labels[b*NN + t];
  __syncthreads();
  for (int e = t; e < TA*NN; e += 256) {
    int j = e / TA, ai = e % TA;
    int tg = (int)out_tgt[(size_t)(b*NN + j)*AA + a0 + ai];
    ltg[ai][j] = lab[tg];
  }
  if (t < TA) { nr[t] = g_norm[b*AA + a0 + t]; fgi[t] = g_fgcnt[b*AA + a0 + t]; }
  __syncthreads();
  int F = g_fgcol[b];
  #pragma unroll
  for (int k = 0; k < (TA*CC)/256; ++k) {
    int p = t + k*256;
    int ai = p / CC, c = p % CC;
    int cnt = 0;
    #pragma unroll
    for (int j = 0; j < NN; ++j) cnt += (ltg[ai][j] == c) ? 1 : 0;
    bool ind = (c == F) ? ((cnt + fgi[ai]) != NN) : (cnt > 0);
    out_scores[(size_t)(b*AA + a0)*CC + p] = ind ? nr[ai] : 0.0f;
  }
}

extern "C" void kernel_launch(void* const* d_in, const int* in_sizes, int n_in,
                              void* d_out, int out_size, void* d_ws, size_t ws_size,
                              hipStream_t stream) {
  const float* pd_scores = (const float*)d_in[0];
  const float* pd_bboxes = (const float*)d_in[1];
  const float* anc       = (const float*)d_in[2];
  const int*   gt_labels = (const int*)d_in[3];
  // d_in[4] = gt_probs (unused by reference output path)
  const float* gt_bboxes = (const float*)d_in[5];
  const float* mask_gt   = (const float*)d_in[6];

  float* out_bbox   = (float*)d_out;
  float* out_scores = out_bbox + (size_t)BB*AA*4;
  float* out_fg     = out_scores + (size_t)BB*AA*CC;
  float* out_tgt    = out_fg + (size_t)BB*AA;

  k1<<<(BB*NN*AA + 255)/256, 256, 0, stream>>>(pd_scores, pd_bboxes, anc, gt_labels, gt_bboxes);
  k2<<<BB*NN, 64, 0, stream>>>(mask_gt);
  dim3 g3a((AA + 255)/256, BB);
  k3a<<<g3a, 256, 0, stream>>>(gt_bboxes, gt_labels, out_bbox, out_fg, out_tgt);
  k3b<<<1, 64, 0, stream>>>();
  dim3 g3c(AA/TA, BB);
  k3c<<<g3c, 256, 0, stream>>>(gt_labels, out_tgt, out_scores);
}

// Round 2
// 185.227 us; speedup vs baseline: 1.2448x; 1.2448x over previous
//
#include <hip/hip_runtime.h>
#include <math.h>

#define BB 32
#define NN 32
#define AA 8400
#define CC 80
#define TK 13
#define TA 16

// Static device scratch. Fully rewritten each call (deterministic).
__device__ float    g_metrics[BB*NN*AA];
__device__ float    g_overlaps[BB*NN*AA];
__device__ unsigned g_inmask[BB*AA];
__device__ unsigned g_posmask[BB*AA];
__device__ unsigned g_tgtmask[BB*AA];
__device__ float    g_posalign[BB*NN];
__device__ float    g_posov[BB*NN];
__device__ float    g_norm[BB*AA];
__device__ int      g_fgcnt[BB*AA];
__device__ int      g_S[BB*CC];
__device__ int      g_fgcol[BB];

// K1: one thread per (b,a); loop over 32 gts. Writes metrics/overlaps rows,
// packs mask_in into a u32 bitmask, zeroes posmask and S.
__global__ __launch_bounds__(256) void k1(const float* __restrict__ pd_scores,
                                          const float* __restrict__ pd_bboxes,
                                          const float* __restrict__ anc,
                                          const int* __restrict__ gt_labels,
                                          const float* __restrict__ gt_bboxes) {
  int b = blockIdx.y;
  int t = threadIdx.x;
  int a = blockIdx.x*256 + t;
  __shared__ __align__(16) float4 gbox[NN];
  __shared__ float gsx[NN], gsy[NN], garea[NN], gatan[NN];
  __shared__ int glab[NN];
  if (t < NN) {
    float4 g = *(const float4*)&gt_bboxes[(b*NN + t)*4];
    gbox[t] = g;
    float w2 = g.z - g.x, h2 = g.w - g.y;
    gsx[t] = g.x + g.z; gsy[t] = g.y + g.w;
    garea[t] = w2*h2;
    gatan[t] = atanf(w2 / (h2 + 1e-7f));
    glab[t] = gt_labels[b*NN + t];
  }
  if (blockIdx.x == 0 && t < CC) g_S[b*CC + t] = 0;
  __syncthreads();
  if (a >= AA) return;
  float4 p = *(const float4*)&pd_bboxes[(size_t)(b*AA + a)*4];
  float2 an = ((const float2*)anc)[a];
  float w1 = p.z - p.x, h1 = p.w - p.y;
  float area1 = w1*h1;
  float psx = p.x + p.z, psy = p.y + p.w;
  float atan1 = atanf(w1 / (h1 + 1e-7f));
  const float* srow = &pd_scores[(size_t)(b*AA + a)*CC];
  const float c4pi2 = (float)(4.0 / (M_PI * M_PI));
  unsigned inm = 0u;
  #pragma unroll 4
  for (int j = 0; j < NN; ++j) {
    float4 g = gbox[j];
    float iw = fmaxf(fminf(p.z, g.z) - fmaxf(p.x, g.x), 0.0f);
    float ih = fmaxf(fminf(p.w, g.w) - fmaxf(p.y, g.y), 0.0f);
    float inter = iw * ih;
    float uni = area1 + garea[j] - inter + 1e-7f;
    float iou = inter / uni;
    float cw = fmaxf(p.z, g.z) - fminf(p.x, g.x);
    float ch = fmaxf(p.w, g.w) - fminf(p.y, g.y);
    float c2 = cw*cw + ch*ch + 1e-7f;
    float dx = gsx[j] - psx, dy = gsy[j] - psy;
    float rho2 = (dx*dx + dy*dy) * 0.25f;
    float dat = gatan[j] - atan1;
    float v = c4pi2 * dat * dat;
    float alpha = v / (v - iou + (1.0f + 1e-7f));
    float ov = fmaxf(iou - (rho2/c2 + v*alpha), 0.0f);
    float mn = fminf(fminf(an.x - g.x, an.y - g.y), fminf(g.z - an.x, g.w - an.y));
    bool mi = mn > 1e-9f;
    float ov2 = ov*ov;
    float align = srow[glab[j]] * (ov2*ov2*ov2);
    size_t o = (size_t)(b*NN + j)*AA + a;
    g_metrics[o]  = mi ? align : 0.0f;
    g_overlaps[o] = ov;
    inm |= mi ? (1u << j) : 0u;
  }
  g_inmask[b*AA + a]  = inm;
  g_posmask[b*AA + a] = 0u;
}

// K2: one wave per (b,j). Single coalesced float4 sweep with per-lane sorted
// top-13 (keys = valbits<<32 | ~idx -> exact lax.top_k tie-break), then a
// 13-round shuffle merge. Scatters posmask bits; computes pos_align/pos_ov.
__global__ __launch_bounds__(64) void k2(const float* __restrict__ mask_gt) {
  int bj = blockIdx.x;
  int b = bj / NN, j = bj % NN;
  int lane = threadIdx.x;
  const float* mrow = &g_metrics[(size_t)bj*AA];
  unsigned long long tk[TK];
  #pragma unroll
  for (int i = 0; i < TK; ++i) tk[i] = 0ull;

  auto ins = [&](float val, unsigned a) {
    unsigned long long key = ((unsigned long long)__float_as_uint(val) << 32)
                           | (unsigned long long)(0xFFFFFFFFu - a);
    if (key > tk[TK-1]) {
      tk[TK-1] = key;
      #pragma unroll
      for (int i = TK-1; i > 0; --i) {
        if (tk[i] > tk[i-1]) {
          unsigned long long tmp = tk[i-1]; tk[i-1] = tk[i]; tk[i] = tmp;
        }
      }
    }
  };

  for (int i = lane; i < AA/4; i += 64) {
    float4 m4 = ((const float4*)mrow)[i];
    unsigned a0 = 4u*(unsigned)i;
    ins(m4.x, a0 + 0u);
    ins(m4.y, a0 + 1u);
    ins(m4.z, a0 + 2u);
    ins(m4.w, a0 + 3u);
  }

  // 13-round global max-extract; lane r keeps selection r.
  unsigned long long cur = tk[0];
  unsigned mysel_a = 0u; float mysel_v = 0.0f;
  for (int r = 0; r < TK; ++r) {
    unsigned long long m = cur;
    #pragma unroll
    for (int o = 32; o > 0; o >>= 1) {
      unsigned long long other = __shfl_xor(m, o, 64);
      if (other > m) m = other;
    }
    if (cur == m) {   // unique winner advances
      #pragma unroll
      for (int i = 0; i < TK-1; ++i) tk[i] = tk[i+1];
      tk[TK-1] = 0ull;
      cur = tk[0];
    }
    if (lane == r) {
      mysel_a = 0xFFFFFFFFu - (unsigned)(m & 0xFFFFFFFFull);
      mysel_v = __uint_as_float((unsigned)(m >> 32));
    }
  }

  bool valid = (mask_gt[bj] != 0.0f);
  float pa = 0.0f, po = 0.0f;
  if (lane < TK && valid) {
    unsigned im = g_inmask[b*AA + mysel_a];
    if ((im >> j) & 1u) {
      atomicOr(&g_posmask[b*AA + mysel_a], 1u << j);
      pa = mysel_v;
      po = g_overlaps[(size_t)bj*AA + mysel_a];
    }
  }
  #pragma unroll
  for (int o = 32; o > 0; o >>= 1) {
    pa = fmaxf(pa, __shfl_xor(pa, o, 64));
    po = fmaxf(po, __shfl_xor(po, o, 64));
  }
  if (lane == 0) { g_posalign[bj] = pa; g_posov[bj] = po; }
}

// K3a: per (b,a): tgt, fg, bbox, norm, tgtmask; class histogram S.
__global__ __launch_bounds__(256) void k3a(const float* __restrict__ gt_bboxes,
                                           const int* __restrict__ gt_labels,
                                           float* __restrict__ out_bbox,
                                           float* __restrict__ out_fg,
                                           float* __restrict__ out_tgt) {
  int b = blockIdx.y;
  int t = threadIdx.x;
  int a = blockIdx.x*256 + t;
  __shared__ __align__(16) float4 gbox[NN];
  __shared__ int lab[NN];
  __shared__ float pal[NN], pov[NN];
  __shared__ int Sl[CC];
  if (t < NN) {
    gbox[t] = *(const float4*)&gt_bboxes[(b*NN + t)*4];
    lab[t]  = gt_labels[b*NN + t];
    pal[t]  = g_posalign[b*NN + t];
    pov[t]  = g_posov[b*NN + t];
  }
  if (t < CC) Sl[t] = 0;
  __syncthreads();
  if (a < AA) {
    unsigned pm = g_posmask[b*AA + a];
    float ov[NN];
    #pragma unroll
    for (int j = 0; j < NN; ++j) ov[j] = g_overlaps[(size_t)(b*NN + j)*AA + a];
    float maxo = ov[0];
    #pragma unroll
    for (int j = 1; j < NN; ++j) maxo = fmaxf(maxo, ov[j]);
    unsigned tm = 0u;
    int jmax = 0;
    float nrm = 0.0f;
    #pragma unroll
    for (int j = 0; j < NN; ++j) {
      bool m = (pm >> j) & 1u;
      int tj = (m && (ov[j] == maxo)) ? j : 0;
      out_tgt[(size_t)(b*NN + j)*AA + a] = (float)tj;
      if (tj) { tm |= (1u << j); jmax = (tj > jmax) ? tj : jmax; }
      if (m) {
        float al = g_metrics[(size_t)(b*NN + j)*AA + a];
        nrm = fmaxf(nrm, al * pov[j] / (pal[j] + 1e-9f));
      }
    }
    int fg = __popc(pm);
    int z = NN - __popc(tm);
    atomicAdd(&Sl[lab[0]], z);
    unsigned tmp = tm;
    while (tmp) { int jj = __ffs(tmp) - 1; tmp &= tmp - 1; atomicAdd(&Sl[lab[jj]], 1); }
    g_tgtmask[b*AA + a] = tm;
    g_fgcnt[b*AA + a]   = fg;
    g_norm[b*AA + a]    = nrm;
    out_fg[b*AA + a]    = fg ? 1.0f : 0.0f;
    *(float4*)&out_bbox[(size_t)(b*AA + a)*4] = gbox[jmax];
  }
  __syncthreads();
  if (t < CC) atomicAdd(&g_S[b*CC + t], Sl[t]);
}

// K3b: fg_columns[b] = argmax_c S[b,c] (first max)
__global__ __launch_bounds__(64) void k3b() {
  int b = threadIdx.x;
  if (b < BB) {
    int best = -1, bc = 0;
    for (int c = 0; c < CC; ++c) { int s = g_S[b*CC + c]; if (s > best) { best = s; bc = c; } }
    g_fgcol[b] = bc;
  }
}

// K3c: target_scores[b,a,c] = hard * norm, from tgtmask (4B instead of 128B).
__global__ __launch_bounds__(256) void k3c(const int* __restrict__ gt_labels,
                                           float* __restrict__ out_scores) {
  int b = blockIdx.y;
  int t = threadIdx.x;
  int a0 = blockIdx.x * TA;
  __shared__ int lab[NN];
  __shared__ unsigned lm[TA][3];
  __shared__ float nr[TA];
  __shared__ int hF[TA];
  if (t < NN) lab[t] = gt_labels[b*NN + t];
  __syncthreads();
  int F = g_fgcol[b];
  if (t < TA) {
    int a = a0 + t;
    unsigned tm = g_tgtmask[b*AA + a];
    int fg = g_fgcnt[b*AA + a];
    nr[t] = g_norm[b*AA + a];
    unsigned m0 = 0u, m1 = 0u, m2 = 0u;
    int z = NN - __popc(tm);
    int l0 = lab[0];
    if (l0 < 32) m0 |= 1u << l0; else if (l0 < 64) m1 |= 1u << (l0 - 32); else m2 |= 1u << (l0 - 64);
    int cntF = (l0 == F) ? z : 0;
    unsigned tmp = tm;
    while (tmp) {
      int jj = __ffs(tmp) - 1; tmp &= tmp - 1;
      int l = lab[jj];
      if (l < 32) m0 |= 1u << l; else if (l < 64) m1 |= 1u << (l - 32); else m2 |= 1u << (l - 64);
      cntF += (l == F) ? 1 : 0;
    }
    lm[t][0] = m0; lm[t][1] = m1; lm[t][2] = m2;
    hF[t] = ((cntF + fg) != NN) ? 1 : 0;
  }
  __syncthreads();
  #pragma unroll
  for (int k = 0; k < (TA*CC)/256; ++k) {
    int p = t + k*256;
    int ai = p / CC, c = p % CC;
    bool ind = (c == F) ? (hF[ai] != 0) : ((lm[ai][c >> 5] >> (c & 31)) & 1u);
    out_scores[(size_t)(b*AA + a0)*CC + p] = ind ? nr[ai] : 0.0f;
  }
}

extern "C" void kernel_launch(void* const* d_in, const int* in_sizes, int n_in,
                              void* d_out, int out_size, void* d_ws, size_t ws_size,
                              hipStream_t stream) {
  const float* pd_scores = (const float*)d_in[0];
  const float* pd_bboxes = (const float*)d_in[1];
  const float* anc       = (const float*)d_in[2];
  const int*   gt_labels = (const int*)d_in[3];
  const float* gt_bboxes = (const float*)d_in[5];
  const float* mask_gt   = (const float*)d_in[6];

  float* out_bbox   = (float*)d_out;
  float* out_scores = out_bbox + (size_t)BB*AA*4;
  float* out_fg     = out_scores + (size_t)BB*AA*CC;
  float* out_tgt    = out_fg + (size_t)BB*AA;

  dim3 gba((AA + 255)/256, BB);
  k1<<<gba, 256, 0, stream>>>(pd_scores, pd_bboxes, anc, gt_labels, gt_bboxes);
  k2<<<BB*NN, 64, 0, stream>>>(mask_gt);
  k3a<<<gba, 256, 0, stream>>>(gt_bboxes, gt_labels, out_bbox, out_fg, out_tgt);
  k3b<<<1, 64, 0, stream>>>();
  dim3 g3c(AA/TA, BB);
  k3c<<<g3c, 256, 0, stream>>>(gt_labels, out_scores);
}

// Round 3
// 146.504 us; speedup vs baseline: 1.5738x; 1.2643x over previous
//
#include <hip/hip_runtime.h>
#include <math.h>

#define BB 32
#define NN 32
#define AA 8400
#define CC 80
#define TK 13
#define TA 16

// Static device scratch. Fully rewritten each call (deterministic).
__device__ float    g_metrics[BB*NN*AA];
__device__ float    g_overlaps[BB*NN*AA];
__device__ unsigned g_inmask[BB*AA];
__device__ unsigned g_posmask[BB*AA];
__device__ unsigned g_tgtmask[BB*AA];
__device__ float    g_posalign[BB*NN];
__device__ float    g_posov[BB*NN];
__device__ float    g_norm[BB*AA];
__device__ int      g_fgcnt[BB*AA];
__device__ int      g_S[BB*CC];
__device__ int      g_fgcol[BB];

// K1: one thread per (b,a); loop over 32 gts. pd_scores is read fully
// coalesced and the <=32 needed label columns staged into padded LDS.
__global__ __launch_bounds__(256) void k1(const float* __restrict__ pd_scores,
                                          const float* __restrict__ pd_bboxes,
                                          const float* __restrict__ anc,
                                          const int* __restrict__ gt_labels,
                                          const float* __restrict__ gt_bboxes) {
  int b = blockIdx.y;
  int t = threadIdx.x;
  int a0 = blockIdx.x*256;
  int a = a0 + t;
  __shared__ __align__(16) float4 gbox[NN];
  __shared__ float gsx[NN], gsy[NN], garea[NN], gatan[NN];
  __shared__ int gslot[NN];
  __shared__ int cls2slot[CC];
  __shared__ float smem_s[256][NN+1];
  if (t < CC) {
    cls2slot[t] = -1;
    if (blockIdx.x == 0) g_S[b*CC + t] = 0;
  }
  if (t < NN) {
    float4 g = *(const float4*)&gt_bboxes[(b*NN + t)*4];
    gbox[t] = g;
    float w2 = g.z - g.x, h2 = g.w - g.y;
    gsx[t] = g.x + g.z; gsy[t] = g.y + g.w;
    garea[t] = w2*h2;
    gatan[t] = atanf(w2 / (h2 + 1e-7f));
  }
  __syncthreads();
  if (t == 0) {
    for (int j = 0; j < NN; ++j) {
      int l = gt_labels[b*NN + j];
      if (cls2slot[l] < 0) cls2slot[l] = j;
      gslot[j] = cls2slot[l];
    }
  }
  __syncthreads();
  // Coalesced staging of pd_scores[b, a0:a0+256, :] -> needed label slots.
  int arem = AA - a0; if (arem > 256) arem = 256;
  const float4* sbase = (const float4*)&pd_scores[(size_t)(b*AA + a0)*CC];
  #pragma unroll
  for (int k = 0; k < (256*CC)/(4*256); ++k) {
    int f4 = t + k*256;
    int fi = f4*4;
    int row = fi / CC;
    int col = fi - row*CC;
    if (row < arem) {
      float4 v = sbase[f4];
      int s;
      s = cls2slot[col];     if (s >= 0) smem_s[row][s] = v.x;
      s = cls2slot[col + 1]; if (s >= 0) smem_s[row][s] = v.y;
      s = cls2slot[col + 2]; if (s >= 0) smem_s[row][s] = v.z;
      s = cls2slot[col + 3]; if (s >= 0) smem_s[row][s] = v.w;
    }
  }
  __syncthreads();
  if (a >= AA) return;
  float4 p = *(const float4*)&pd_bboxes[(size_t)(b*AA + a)*4];
  float2 an = ((const float2*)anc)[a];
  float w1 = p.z - p.x, h1 = p.w - p.y;
  float area1 = w1*h1;
  float psx = p.x + p.z, psy = p.y + p.w;
  float atan1 = atanf(w1 / (h1 + 1e-7f));
  const float c4pi2 = (float)(4.0 / (M_PI * M_PI));
  unsigned inm = 0u;
  #pragma unroll 4
  for (int j = 0; j < NN; ++j) {
    float4 g = gbox[j];
    float iw = fmaxf(fminf(p.z, g.z) - fmaxf(p.x, g.x), 0.0f);
    float ih = fmaxf(fminf(p.w, g.w) - fmaxf(p.y, g.y), 0.0f);
    float inter = iw * ih;
    float uni = area1 + garea[j] - inter + 1e-7f;
    float iou = inter / uni;
    float cw = fmaxf(p.z, g.z) - fminf(p.x, g.x);
    float ch = fmaxf(p.w, g.w) - fminf(p.y, g.y);
    float c2 = cw*cw + ch*ch + 1e-7f;
    float dx = gsx[j] - psx, dy = gsy[j] - psy;
    float rho2 = (dx*dx + dy*dy) * 0.25f;
    float dat = gatan[j] - atan1;
    float v = c4pi2 * dat * dat;
    float alpha = v / (v - iou + (1.0f + 1e-7f));
    float ov = fmaxf(iou - (rho2/c2 + v*alpha), 0.0f);
    float mn = fminf(fminf(an.x - g.x, an.y - g.y), fminf(g.z - an.x, g.w - an.y));
    bool mi = mn > 1e-9f;
    float ov2 = ov*ov;
    float align = smem_s[t][gslot[j]] * (ov2*ov2*ov2);
    size_t o = (size_t)(b*NN + j)*AA + a;
    g_metrics[o]  = mi ? align : 0.0f;
    g_overlaps[o] = ov;
    inm |= mi ? (1u << j) : 0u;
  }
  g_inmask[b*AA + a]  = inm;
  g_posmask[b*AA + a] = 0u;
}

// K2: one wave per (b,j). Single coalesced float4 sweep with per-lane sorted
// top-13 (keys = valbits<<32 | ~idx -> exact lax.top_k tie-break), then a
// 13-round shuffle merge. Scatters posmask bits; computes pos_align/pos_ov.
__global__ __launch_bounds__(64) void k2(const float* __restrict__ mask_gt) {
  int bj = blockIdx.x;
  int b = bj / NN, j = bj % NN;
  int lane = threadIdx.x;
  const float* mrow = &g_metrics[(size_t)bj*AA];
  unsigned long long tk[TK];
  #pragma unroll
  for (int i = 0; i < TK; ++i) tk[i] = 0ull;

  auto ins = [&](float val, unsigned a) {
    unsigned long long key = ((unsigned long long)__float_as_uint(val) << 32)
                           | (unsigned long long)(0xFFFFFFFFu - a);
    if (key > tk[TK-1]) {
      tk[TK-1] = key;
      #pragma unroll
      for (int i = TK-1; i > 0; --i) {
        if (tk[i] > tk[i-1]) {
          unsigned long long tmp = tk[i-1]; tk[i-1] = tk[i]; tk[i] = tmp;
        }
      }
    }
  };

  for (int i = lane; i < AA/4; i += 64) {
    float4 m4 = ((const float4*)mrow)[i];
    unsigned a0 = 4u*(unsigned)i;
    ins(m4.x, a0 + 0u);
    ins(m4.y, a0 + 1u);
    ins(m4.z, a0 + 2u);
    ins(m4.w, a0 + 3u);
  }

  // 13-round global max-extract; lane r keeps selection r.
  unsigned long long cur = tk[0];
  unsigned mysel_a = 0u; float mysel_v = 0.0f;
  for (int r = 0; r < TK; ++r) {
    unsigned long long m = cur;
    #pragma unroll
    for (int o = 32; o > 0; o >>= 1) {
      unsigned long long other = __shfl_xor(m, o, 64);
      if (other > m) m = other;
    }
    if (cur == m) {   // unique winner advances
      #pragma unroll
      for (int i = 0; i < TK-1; ++i) tk[i] = tk[i+1];
      tk[TK-1] = 0ull;
      cur = tk[0];
    }
    if (lane == r) {
      mysel_a = 0xFFFFFFFFu - (unsigned)(m & 0xFFFFFFFFull);
      mysel_v = __uint_as_float((unsigned)(m >> 32));
    }
  }

  bool valid = (mask_gt[bj] != 0.0f);
  float pa = 0.0f, po = 0.0f;
  if (lane < TK && valid) {
    unsigned im = g_inmask[b*AA + mysel_a];
    if ((im >> j) & 1u) {
      atomicOr(&g_posmask[b*AA + mysel_a], 1u << j);
      pa = mysel_v;
      po = g_overlaps[(size_t)bj*AA + mysel_a];
    }
  }
  #pragma unroll
  for (int o = 32; o > 0; o >>= 1) {
    pa = fmaxf(pa, __shfl_xor(pa, o, 64));
    po = fmaxf(po, __shfl_xor(po, o, 64));
  }
  if (lane == 0) { g_posalign[bj] = pa; g_posov[bj] = po; }
}

// K3a: per (b,a): tgt, fg, bbox, norm, tgtmask; class histogram S.
__global__ __launch_bounds__(256) void k3a(const float* __restrict__ gt_bboxes,
                                           const int* __restrict__ gt_labels,
                                           float* __restrict__ out_bbox,
                                           float* __restrict__ out_fg,
                                           float* __restrict__ out_tgt) {
  int b = blockIdx.y;
  int t = threadIdx.x;
  int a = blockIdx.x*256 + t;
  __shared__ __align__(16) float4 gbox[NN];
  __shared__ int lab[NN];
  __shared__ float pal[NN], pov[NN];
  __shared__ int Sl[CC];
  if (t < NN) {
    gbox[t] = *(const float4*)&gt_bboxes[(b*NN + t)*4];
    lab[t]  = gt_labels[b*NN + t];
    pal[t]  = g_posalign[b*NN + t];
    pov[t]  = g_posov[b*NN + t];
  }
  if (t < CC) Sl[t] = 0;
  __syncthreads();
  if (a < AA) {
    unsigned pm = g_posmask[b*AA + a];
    float ov[NN];
    #pragma unroll
    for (int j = 0; j < NN; ++j) ov[j] = g_overlaps[(size_t)(b*NN + j)*AA + a];
    float maxo = ov[0];
    #pragma unroll
    for (int j = 1; j < NN; ++j) maxo = fmaxf(maxo, ov[j]);
    unsigned tm = 0u;
    int jmax = 0;
    float nrm = 0.0f;
    #pragma unroll
    for (int j = 0; j < NN; ++j) {
      bool m = (pm >> j) & 1u;
      int tj = (m && (ov[j] == maxo)) ? j : 0;
      out_tgt[(size_t)(b*NN + j)*AA + a] = (float)tj;
      if (tj) { tm |= (1u << j); jmax = (tj > jmax) ? tj : jmax; }
      if (m) {
        float al = g_metrics[(size_t)(b*NN + j)*AA + a];
        nrm = fmaxf(nrm, al * pov[j] / (pal[j] + 1e-9f));
      }
    }
    int fg = __popc(pm);
    int z = NN - __popc(tm);
    atomicAdd(&Sl[lab[0]], z);
    unsigned tmp = tm;
    while (tmp) { int jj = __ffs(tmp) - 1; tmp &= tmp - 1; atomicAdd(&Sl[lab[jj]], 1); }
    g_tgtmask[b*AA + a] = tm;
    g_fgcnt[b*AA + a]   = fg;
    g_norm[b*AA + a]    = nrm;
    out_fg[b*AA + a]    = fg ? 1.0f : 0.0f;
    *(float4*)&out_bbox[(size_t)(b*AA + a)*4] = gbox[jmax];
  }
  __syncthreads();
  if (t < CC) atomicAdd(&g_S[b*CC + t], Sl[t]);
}

// K3b: fg_columns[b] = argmax_c S[b,c] (first max)
__global__ __launch_bounds__(64) void k3b() {
  int b = threadIdx.x;
  if (b < BB) {
    int best = -1, bc = 0;
    for (int c = 0; c < CC; ++c) { int s = g_S[b*CC + c]; if (s > best) { best = s; bc = c; } }
    g_fgcol[b] = bc;
  }
}

// K3c: target_scores[b,a,c] = hard * norm, from tgtmask (4B instead of 128B).
__global__ __launch_bounds__(256) void k3c(const int* __restrict__ gt_labels,
                                           float* __restrict__ out_scores) {
  int b = blockIdx.y;
  int t = threadIdx.x;
  int a0 = blockIdx.x * TA;
  __shared__ int lab[NN];
  __shared__ unsigned lm[TA][3];
  __shared__ float nr[TA];
  __shared__ int hF[TA];
  if (t < NN) lab[t] = gt_labels[b*NN + t];
  __syncthreads();
  int F = g_fgcol[b];
  if (t < TA) {
    int a = a0 + t;
    unsigned tm = g_tgtmask[b*AA + a];
    int fg = g_fgcnt[b*AA + a];
    nr[t] = g_norm[b*AA + a];
    unsigned m0 = 0u, m1 = 0u, m2 = 0u;
    int z = NN - __popc(tm);
    int l0 = lab[0];
    if (l0 < 32) m0 |= 1u << l0; else if (l0 < 64) m1 |= 1u << (l0 - 32); else m2 |= 1u << (l0 - 64);
    int cntF = (l0 == F) ? z : 0;
    unsigned tmp = tm;
    while (tmp) {
      int jj = __ffs(tmp) - 1; tmp &= tmp - 1;
      int l = lab[jj];
      if (l < 32) m0 |= 1u << l; else if (l < 64) m1 |= 1u << (l - 32); else m2 |= 1u << (l - 64);
      cntF += (l == F) ? 1 : 0;
    }
    lm[t][0] = m0; lm[t][1] = m1; lm[t][2] = m2;
    hF[t] = ((cntF + fg) != NN) ? 1 : 0;
  }
  __syncthreads();
  #pragma unroll
  for (int k = 0; k < (TA*CC)/256; ++k) {
    int p = t + k*256;
    int ai = p / CC, c = p % CC;
    bool ind = (c == F) ? (hF[ai] != 0) : ((lm[ai][c >> 5] >> (c & 31)) & 1u);
    out_scores[(size_t)(b*AA + a0)*CC + p] = ind ? nr[ai] : 0.0f;
  }
}

extern "C" void kernel_launch(void* const* d_in, const int* in_sizes, int n_in,
                              void* d_out, int out_size, void* d_ws, size_t ws_size,
                              hipStream_t stream) {
  const float* pd_scores = (const float*)d_in[0];
  const float* pd_bboxes = (const float*)d_in[1];
  const float* anc       = (const float*)d_in[2];
  const int*   gt_labels = (const int*)d_in[3];
  const float* gt_bboxes = (const float*)d_in[5];
  const float* mask_gt   = (const float*)d_in[6];

  float* out_bbox   = (float*)d_out;
  float* out_scores = out_bbox + (size_t)BB*AA*4;
  float* out_fg     = out_scores + (size_t)BB*AA*CC;
  float* out_tgt    = out_fg + (size_t)BB*AA;

  dim3 gba((AA + 255)/256, BB);
  k1<<<gba, 256, 0, stream>>>(pd_scores, pd_bboxes, anc, gt_labels, gt_bboxes);
  k2<<<BB*NN, 64, 0, stream>>>(mask_gt);
  k3a<<<gba, 256, 0, stream>>>(gt_bboxes, gt_labels, out_bbox, out_fg, out_tgt);
  k3b<<<1, 64, 0, stream>>>();
  dim3 g3c(AA/TA, BB);
  k3c<<<g3c, 256, 0, stream>>>(gt_labels, out_scores);
}